// Round 17
// baseline (1255.660 us; speedup 1.0000x reference)
//
#include <hip/hip_runtime.h>
#include <hip/hip_bf16.h>
#include <cstdint>
#include <cstddef>
#include <type_traits>

#define HIDC 128   // per-head channels

typedef __attribute__((ext_vector_type(8))) short short8v;
typedef __attribute__((ext_vector_type(4))) float float4v;

// ---------- typed load/store (fp32 or bf16 storage) ----------
__device__ __forceinline__ float loadT(const float* p){ return *p; }
__device__ __forceinline__ float loadT(const __hip_bfloat16* p){ return __bfloat162float(*p); }
__device__ __forceinline__ void  storeT(float* p, float v){ *p = v; }
__device__ __forceinline__ void  storeT(__hip_bfloat16* p, float v){ *p = __float2bfloat16(v); }

__device__ __forceinline__ short f2bf(float f){
  __hip_bfloat16 h = __float2bfloat16(f);
  return *reinterpret_cast<short*>(&h);
}
__device__ __forceinline__ float bfbits2f(short s){
  return __uint_as_float(((unsigned)(unsigned short)s) << 16);
}

// bijective XCD-chunk swizzle (m204): contiguous logical range per XCD
__device__ __forceinline__ int xcd_chunk(int orig, int nwg){
  int xcd = orig & 7, pos = orig >> 3;
  int q = nwg >> 3, r = nwg & 7;
  return (xcd < r ? xcd*(q+1) : r*(q+1) + (xcd - r)*q) + pos;
}

// swizzled LDS index (in shorts); k must be a multiple of 8 for b128 ops
__device__ __forceinline__ int swz(int row, int k){ return (row*32 + k) ^ ((row & 7) << 3); }

// ---------------- MFMA bf16 GEMM: C[M,0..Nb) = A[M,K] @ B[K,Nb] ----------------
// BM=128, BN=64, BK=32; 256 threads = 4 waves, each a 64x32 output tile.
// T1 XCD-chunk swizzle. DMA path (bf16 A, K%32==0, full row tile):
// 2-phase double-buffered pipeline (R15: proven WIN).
template<typename TA, typename TC, bool BIAS, bool RELU>
__global__ __launch_bounds__(256)
void mfma_gemm_kernel(const TA* __restrict__ A, const float* __restrict__ B,
                      const float* __restrict__ bias, TC* __restrict__ C,
                      int M, int Nb, int K, int ldc)
{
  __shared__ short As[2][128*32];
  __shared__ short Bs[2][64*32];

  const int nwg = gridDim.x * gridDim.y;
  int logical = xcd_chunk(blockIdx.y * gridDim.x + blockIdx.x, nwg);
  const int bx = logical % gridDim.x;
  const int by = logical / gridDim.x;

  const int tid  = threadIdx.x;
  const int brow = by * 128;
  const int bcol = bx * 64;
  const int lane = tid & 63;
  const int wave = tid >> 6;
  const int wm = (wave >> 1) * 64;
  const int wn = (wave & 1) * 32;
  const int l15 = lane & 15;
  const int kq  = lane >> 4;

  float4v acc[4][2];
  #pragma unroll
  for (int i = 0; i < 4; i++)
    #pragma unroll
    for (int j = 0; j < 2; j++)
      #pragma unroll
      for (int r2 = 0; r2 < 4; r2++) acc[i][j][r2] = 0.f;

  const int am  = tid >> 1;
  const int akb = (tid & 1) * 16;
  const int bn  = tid & 63;
  const int bkc = tid >> 6;

  const bool dma_ok = std::is_same<TA, __hip_bfloat16>::value &&
                      ((K & 31) == 0) && (brow + 128 <= M);
  int dma_r[2], dma_c[2];
  #pragma unroll
  for (int i = 0; i < 2; i++) {
    int j = (wave*2 + i)*64 + lane;
    int s2 = (j>>2)&1, s3 = (j>>3)&1, s4 = (j>>4)&1;
    int b2 = s2 ^ s4;
    int b1 = ((j>>1)&1) ^ s3;
    int b0 = (j&1) ^ b2;
    int src = (j & ~7) | (b2<<2) | (b1<<1) | b0;
    dma_r[i] = src >> 2;
    dma_c[i] = src & 3;
  }

  if (dma_ok) {
    const short* Ash = reinterpret_cast<const short*>(A);
    const int gcol = bcol + bn;
    const int nt = K >> 5;
    float bv[8];

    #pragma unroll
    for (int i = 0; i < 2; i++) {
      const short* gp = Ash + (size_t)(brow + dma_r[i])*K + dma_c[i]*8;
      __builtin_amdgcn_global_load_lds(
          (const __attribute__((address_space(1))) void*)gp,
          (__attribute__((address_space(3))) void*)&As[0][(wave*2 + i)*512],
          16, 0, 0);
    }
    #pragma unroll
    for (int j = 0; j < 8; j++) {
      int gk = bkc*8 + j;
      bv[j] = (gcol < Nb) ? B[(size_t)gk*Nb + gcol] : 0.f;
    }
    {
      short8v v;
      #pragma unroll
      for (int j = 0; j < 8; j++) v[j] = f2bf(bv[j]);
      *(short8v*)&Bs[0][swz(bn, bkc*8)] = v;
    }
    asm volatile("s_waitcnt vmcnt(0)" ::: "memory");
    __syncthreads();

    int cur = 0;
    for (int t = 0; t < nt; t++) {
      const bool pf = (t + 1 < nt);
      if (pf) {
        const int k0n = (t + 1) << 5;
        #pragma unroll
        for (int i = 0; i < 2; i++) {
          const short* gp = Ash + (size_t)(brow + dma_r[i])*K + k0n + dma_c[i]*8;
          __builtin_amdgcn_global_load_lds(
              (const __attribute__((address_space(1))) void*)gp,
              (__attribute__((address_space(3))) void*)&As[cur^1][(wave*2 + i)*512],
              16, 0, 0);
        }
        #pragma unroll
        for (int j = 0; j < 8; j++) {
          int gk = k0n + bkc*8 + j;
          bv[j] = (gcol < Nb) ? B[(size_t)gk*Nb + gcol] : 0.f;
        }
      }
      {
        short8v bfrag[2];
        #pragma unroll
        for (int ni = 0; ni < 2; ni++)
          bfrag[ni] = *(const short8v*)&Bs[cur][swz(wn + ni*16 + l15, kq*8)];
        #pragma unroll
        for (int mi = 0; mi < 4; mi++) {
          short8v afrag = *(const short8v*)&As[cur][swz(wm + mi*16 + l15, kq*8)];
          #pragma unroll
          for (int ni = 0; ni < 2; ni++)
            acc[mi][ni] = __builtin_amdgcn_mfma_f32_16x16x32_bf16(afrag, bfrag[ni], acc[mi][ni], 0, 0, 0);
        }
      }
      if (pf) {
        short8v v;
        #pragma unroll
        for (int j = 0; j < 8; j++) v[j] = f2bf(bv[j]);
        *(short8v*)&Bs[cur^1][swz(bn, bkc*8)] = v;
      }
      asm volatile("s_waitcnt vmcnt(0)" ::: "memory");
      __syncthreads();
      cur ^= 1;
    }
  } else {
    for (int k0 = 0; k0 < K; k0 += 32) {
      {
        const int gm = brow + am;
        short s[16];
        if constexpr (std::is_same<TA, __hip_bfloat16>::value) {
          if (gm < M && (k0 + akb + 16) <= K) {
            const short8v* p = reinterpret_cast<const short8v*>(
                reinterpret_cast<const short*>(A) + (size_t)gm*K + k0 + akb);
            short8v v0 = p[0];
            *(short8v*)&As[0][swz(am, akb)]     = v0;
            short8v v1 = p[1];
            *(short8v*)&As[0][swz(am, akb + 8)] = v1;
            goto a_done;
          }
        }
        #pragma unroll
        for (int j = 0; j < 16; j++) {
          int gk = k0 + akb + j;
          s[j] = (gm < M && gk < K) ? f2bf(loadT(&A[(size_t)gm*K + gk])) : (short)0;
        }
        {
          short8v v0, v1;
          #pragma unroll
          for (int j = 0; j < 8; j++) { v0[j] = s[j]; v1[j] = s[j+8]; }
          *(short8v*)&As[0][swz(am, akb)]     = v0;
          *(short8v*)&As[0][swz(am, akb + 8)] = v1;
        }
        a_done:;
      }
      {
        const int gcol = bcol + bn;
        short8v v;
        #pragma unroll
        for (int j = 0; j < 8; j++) {
          int gk = k0 + bkc*8 + j;
          v[j] = (gk < K && gcol < Nb) ? f2bf(B[(size_t)gk*Nb + gcol]) : (short)0;
        }
        *(short8v*)&Bs[0][swz(bn, bkc*8)] = v;
      }
      __syncthreads();

      short8v bfrag[2];
      #pragma unroll
      for (int ni = 0; ni < 2; ni++)
        bfrag[ni] = *(const short8v*)&Bs[0][swz(wn + ni*16 + l15, kq*8)];
      #pragma unroll
      for (int mi = 0; mi < 4; mi++) {
        short8v afrag = *(const short8v*)&As[0][swz(wm + mi*16 + l15, kq*8)];
        #pragma unroll
        for (int ni = 0; ni < 2; ni++)
          acc[mi][ni] = __builtin_amdgcn_mfma_f32_16x16x32_bf16(afrag, bfrag[ni], acc[mi][ni], 0, 0, 0);
      }
      __syncthreads();
    }
  }

  #pragma unroll
  for (int mi = 0; mi < 4; mi++) {
    #pragma unroll
    for (int r2 = 0; r2 < 4; r2++) {
      int row = brow + wm + mi*16 + kq*4 + r2;
      if (row >= M) continue;
      #pragma unroll
      for (int ni = 0; ni < 2; ni++) {
        int col = bcol + wn + ni*16 + l15;
        if (col >= Nb) continue;
        float v = acc[mi][ni][r2];
        if (BIAS) v += bias[col];
        if (RELU) v = fmaxf(v, 0.f);
        storeT(&C[(size_t)row*ldc + col], v);
      }
    }
  }
}

// ---------------- per-(node,head) attention scores ----------------
template<typename T>
__global__ void scores_kernel(const T* __restrict__ hW, const float* __restrict__ a_src,
                              const float* __restrict__ a_dst, float* __restrict__ s_src,
                              float* __restrict__ s_dst, int n, int H)
{
  const int lane = threadIdx.x & 63;
  const int wid = blockIdx.x*(blockDim.x>>6) + (threadIdx.x>>6);
  if (wid >= n*H) return;
  const int node = wid / H, h = wid % H;
  const T* row = hW + (size_t)node*H*HIDC + (size_t)h*HIDC;
  float ss = 0.f, sd = 0.f;
  for (int c = lane; c < HIDC; c += 64) {
    float v = loadT(&row[c]);
    ss += v * a_src[h*HIDC + c];
    sd += v * a_dst[h*HIDC + c];
  }
  #pragma unroll
  for (int off = 32; off; off >>= 1) {
    ss += __shfl_down(ss, off);
    sd += __shfl_down(sd, off);
  }
  if (lane == 0) { s_src[wid] = ss; s_dst[wid] = sd; }
}

// ---------------- CSR build (dst-bucketed incoming edges) ----------------
__global__ void deg_count_kernel(const int* __restrict__ ei, int E, int EP, int* __restrict__ deg)
{
  int e = blockIdx.x*blockDim.x + threadIdx.x;
  if (e >= EP) return;
  int d = (e < E) ? ei[E + e] : (e - E);
  atomicAdd(&deg[d], 1);
}

__global__ __launch_bounds__(256)
void scan1_kernel(const int* __restrict__ deg, int* __restrict__ indptr,
                  int* __restrict__ bsum, int n)
{
  __shared__ int sh[256];
  const int b = blockIdx.x, t = threadIdx.x;
  const int base = b*1024 + t*4;
  int v0 = (base+0 < n) ? deg[base+0] : 0;
  int v1 = (base+1 < n) ? deg[base+1] : 0;
  int v2 = (base+2 < n) ? deg[base+2] : 0;
  int v3 = (base+3 < n) ? deg[base+3] : 0;
  int tsum = v0+v1+v2+v3;
  sh[t] = tsum;
  __syncthreads();
  for (int off = 1; off < 256; off <<= 1) {
    int x = (t >= off) ? sh[t-off] : 0;
    __syncthreads();
    sh[t] += x;
    __syncthreads();
  }
  int run = sh[t] - tsum;
  if (base+0 < n) indptr[base+0] = run; run += v0;
  if (base+1 < n) indptr[base+1] = run; run += v1;
  if (base+2 < n) indptr[base+2] = run; run += v2;
  if (base+3 < n) indptr[base+3] = run;
  if (t == 255) bsum[b] = sh[255];
}

__global__ void scan2_kernel(int* __restrict__ bsum, int B)
{
  if (blockIdx.x == 0 && threadIdx.x == 0) {
    int run = 0;
    for (int i = 0; i < B; i++) { int v = bsum[i]; bsum[i] = run; run += v; }
  }
}

__global__ void scan3_kernel(int* __restrict__ indptr, const int* __restrict__ bsum,
                             int n, int total)
{
  int i = blockIdx.x*blockDim.x + threadIdx.x;
  if (i < n) indptr[i] += bsum[i >> 10];
  if (i == 0) indptr[n] = total;
}

__global__ void fill_kernel(const int* __restrict__ ei, int E, int EP,
                            const int* __restrict__ indptr, int* __restrict__ ctr,
                            int* __restrict__ esrc)
{
  int e = blockIdx.x*blockDim.x + threadIdx.x;
  if (e >= EP) return;
  int s, d;
  if (e < E) { s = ei[e]; d = ei[E + e]; } else { s = d = e - E; }
  int pos = indptr[d] + atomicAdd(&ctr[d], 1);
  esrc[pos] = s;
}

// ------- fused segment softmax + gather-aggregate + bias + BN(eval) + ELU -------
// ONE WAVE PER (dst, head); lane owns packed channel pair (2*lane, 2*lane+1).
// Block index XCD-chunk-swizzled: contiguous dst ranges (whole molecules,
// batch_idx sorted) stay on one XCD -> gathered hW rows reused from its L2.
typedef __hip_bfloat16 bf16;

template<int H, bool POOL>
__global__ void csr_attn_agg_kernel(const int* __restrict__ indptr, const int* __restrict__ esrc,
                                    const float* __restrict__ s_src, const float* __restrict__ s_dst,
                                    const bf16* __restrict__ hW, bf16* __restrict__ out, int n,
                                    const float* __restrict__ bias, const float* __restrict__ g,
                                    const float* __restrict__ be, const float* __restrict__ rm,
                                    const float* __restrict__ rv,
                                    const int* __restrict__ batch, float* __restrict__ gsum)
{
  constexpr int HD = H * HIDC;
  const int lane = threadIdx.x & 63;
  const int lblk = xcd_chunk(blockIdx.x, gridDim.x);
  const int wid = lblk*(blockDim.x>>6) + (threadIdx.x>>6);
  if (wid >= n*H) return;
  const int dst = wid / H, h = wid - dst*H;
  const int beg = indptr[dst], end = indptr[dst+1];
  const int deg = end - beg;
  const float sdh = s_dst[dst*H + h];

  float acc0 = 0.f, acc1 = 0.f;
  const unsigned* hw32 = reinterpret_cast<const unsigned*>(hW);

  if (deg <= 64) {
    int sk = (lane < deg) ? esrc[beg + lane] : -1;
    float sc = -3.0e38f;
    if (sk >= 0) {
      float v = s_src[(size_t)sk*H + h] + sdh;
      sc = (v >= 0.f) ? v : 0.2f*v;
    }
    float m, e, den;
    if (deg <= 8) {
      m = sc;
      #pragma unroll
      for (int off = 1; off < 8; off <<= 1) m = fmaxf(m, __shfl_xor(m, off));
      m = __shfl(m, 0);
      e = (sk >= 0) ? __expf(sc - m) : 0.f;
      den = e;
      #pragma unroll
      for (int off = 1; off < 8; off <<= 1) den += __shfl_xor(den, off);
      den = __shfl(den, 0);
    } else {
      m = sc;
      #pragma unroll
      for (int off = 32; off; off >>= 1) m = fmaxf(m, __shfl_xor(m, off));
      e = (sk >= 0) ? __expf(sc - m) : 0.f;
      den = e;
      #pragma unroll
      for (int off = 32; off; off >>= 1) den += __shfl_xor(den, off);
    }
    const float rden = 1.f / (den + 1e-16f);
    for (int k = 0; k < deg; ++k) {
      float a = __shfl(e, k) * rden;
      int s = __shfl(sk, k);
      unsigned w = hw32[(size_t)s*(HD/2) + h*(HIDC/2) + lane];
      acc0 += a * bfbits2f((short)(w & 0xffff));
      acc1 += a * bfbits2f((short)((unsigned)w >> 16));
    }
  } else {
    float m = -3.0e38f;
    for (int k = beg + lane; k < end; k += 64) {
      float v = s_src[(size_t)esrc[k]*H + h] + sdh;
      v = (v >= 0.f) ? v : 0.2f*v;
      m = fmaxf(m, v);
    }
    #pragma unroll
    for (int off = 32; off; off >>= 1) m = fmaxf(m, __shfl_xor(m, off));
    float den = 0.f;
    for (int k = beg + lane; k < end; k += 64) {
      float v = s_src[(size_t)esrc[k]*H + h] + sdh;
      v = (v >= 0.f) ? v : 0.2f*v;
      den += __expf(v - m);
    }
    #pragma unroll
    for (int off = 32; off; off >>= 1) den += __shfl_xor(den, off);
    const float rden = 1.f / (den + 1e-16f);
    for (int k = beg; k < end; ++k) {
      int s = esrc[k];
      float v = s_src[(size_t)s*H + h] + sdh;
      v = (v >= 0.f) ? v : 0.2f*v;
      float a = __expf(v - m) * rden;
      unsigned w = hw32[(size_t)s*(HD/2) + h*(HIDC/2) + lane];
      acc0 += a * bfbits2f((short)(w & 0xffff));
      acc1 += a * bfbits2f((short)((unsigned)w >> 16));
    }
  }

  const int c0 = h*HIDC + 2*lane;
  const int c1 = c0 + 1;
  const float s0 = g[c0] * rsqrtf(rv[c0] + 1e-5f);
  const float s1 = g[c1] * rsqrtf(rv[c1] + 1e-5f);
  float y0 = (acc0 + bias[c0] - rm[c0]) * s0 + be[c0];
  float y1 = (acc1 + bias[c1] - rm[c1]) * s1 + be[c1];
  y0 = (y0 > 0.f) ? y0 : (__expf(y0) - 1.f);
  y1 = (y1 > 0.f) ? y1 : (__expf(y1) - 1.f);

  unsigned* orow32 = reinterpret_cast<unsigned*>(out) + (size_t)dst*(HD/2) + h*(HIDC/2);
  unsigned w = (unsigned)(unsigned short)f2bf(y0) | ((unsigned)(unsigned short)f2bf(y1) << 16);
  orow32[lane] = w;

  if constexpr (POOL) {
    const int grp = batch[dst];
    atomicAdd(&gsum[(size_t)grp*HIDC + 2*lane], y0);
    atomicAdd(&gsum[(size_t)grp*HIDC + 2*lane + 1], y1);
  }
}

// ---------------- per-graph node count ----------------
__global__ void cnt_kernel(const int* __restrict__ batch, float* __restrict__ cnt, int n)
{
  int i = blockIdx.x*blockDim.x + threadIdx.x;
  if (i >= n) return;
  atomicAdd(&cnt[batch[i]], 1.f);
}

__global__ void pool_div_kernel(float* __restrict__ gsum, const float* __restrict__ cnt, int G)
{
  int idx = blockIdx.x*blockDim.x + threadIdx.x;
  if (idx >= G*HIDC) return;
  gsum[idx] /= fmaxf(cnt[idx >> 7], 1.f);
}

// ---------------- mask dtype detection ----------------
__global__ void mask_detect_kernel(const int* __restrict__ m, int nwords, int* __restrict__ flag)
{
  int i = blockIdx.x*blockDim.x + threadIdx.x;
  if (i >= nwords) return;
  unsigned v = (unsigned)m[i];
  if (v > 1u) atomicOr(flag, 1);
}

// ---------------- loss reduces (grid-stride, 1-2 atomics per block) ----------------
__global__ __launch_bounds__(256)
void bce_reduce_kernel(const float* __restrict__ z, const float* __restrict__ ctx,
                       float* __restrict__ out_sum, int n)
{
  __shared__ float sh[256];
  float local = 0.f;
  const long long total = (long long)n * 9;
  for (long long i = (long long)blockIdx.x*blockDim.x + threadIdx.x; i < total;
       i += (long long)gridDim.x*blockDim.x) {
    int row = (int)(i / 9), j = (int)(i - (long long)row*9);
    float zz = z[(size_t)row*32 + j];
    float la = fmaxf(zz, 0.f) + log1pf(expf(-fabsf(zz)));
    local += la - zz * ctx[i];
  }
  sh[threadIdx.x] = local;
  __syncthreads();
  for (int s = 128; s; s >>= 1) {
    if ((int)threadIdx.x < s) sh[threadIdx.x] += sh[threadIdx.x + s];
    __syncthreads();
  }
  if (threadIdx.x == 0) atomicAdd(out_sum, sh[0]);
}

__global__ __launch_bounds__(256)
void mse_mask_reduce_kernel(const float* __restrict__ z, const float* __restrict__ x,
                            const int* __restrict__ mask, const int* __restrict__ bytemode,
                            float* __restrict__ out_sum, float* __restrict__ out_cnt, int n)
{
  __shared__ float sh[256], sh2[256];
  float local = 0.f, cl = 0.f;
  const bool bm = (*bytemode) != 0;
  const long long total = (long long)n * 29;
  for (long long i = (long long)blockIdx.x*blockDim.x + threadIdx.x; i < total;
       i += (long long)gridDim.x*blockDim.x) {
    int row = (int)(i / 29), j = (int)(i - (long long)row*29);
    int mk = bm ? (int)((const unsigned char*)mask)[row] : mask[row];
    if (mk != 0) {
      float dd = z[(size_t)row*32 + j] - x[i];
      local += dd*dd;
      if (j == 0) cl += 1.f;
    }
  }
  sh[threadIdx.x] = local;
  sh2[threadIdx.x] = cl;
  __syncthreads();
  for (int s = 128; s; s >>= 1) {
    if ((int)threadIdx.x < s) { sh[threadIdx.x] += sh[threadIdx.x + s]; sh2[threadIdx.x] += sh2[threadIdx.x + s]; }
    __syncthreads();
  }
  if (threadIdx.x == 0) { atomicAdd(out_sum, sh[0]); atomicAdd(out_cnt, sh2[0]); }
}

__global__ __launch_bounds__(256)
void mse_reduce_kernel(const float* __restrict__ z, const float* __restrict__ props,
                       float* __restrict__ out_sum, int g)
{
  __shared__ float sh[256];
  float local = 0.f;
  const long long total = (long long)g * 9;
  for (long long i = (long long)blockIdx.x*blockDim.x + threadIdx.x; i < total;
       i += (long long)gridDim.x*blockDim.x) {
    int row = (int)(i / 9), j = (int)(i - (long long)row*9);
    float dd = z[(size_t)row*32 + j] - props[i];
    local += dd*dd;
  }
  sh[threadIdx.x] = local;
  __syncthreads();
  for (int s = 128; s; s >>= 1) {
    if ((int)threadIdx.x < s) sh[threadIdx.x] += sh[threadIdx.x + s];
    __syncthreads();
  }
  if (threadIdx.x == 0) atomicAdd(out_sum, sh[0]);
}

__global__ void finalize_kernel(const float* __restrict__ scal, float* __restrict__ out,
                                float nf, float gf)
{
  out[0] = scal[0]/nf + scal[1]/gf + 0.5f*(scal[2]/(scal[3]*29.f));
}

__global__ void write_zero_kernel(float* __restrict__ out){ out[0] = 0.f; }

// ---------------- pipeline (bf16 node-feature storage) ----------------
static void run_pipeline(void* const* d_in, hipStream_t stream, float* d_out,
                         bf16* buf1, bf16* buf2, float* ssrc, float* sdst,
                         int* indptr, int* deg, int* ctr, int* bsum, int* esrc,
                         float* gemb, float* cnt, float* r3, float* pz, float* scal, int* flag,
                         int N, int E, int G)
{
  const float* x     = (const float*)d_in[0];
  const int*   ei    = (const int*)d_in[1];
  const int*   batch = (const int*)d_in[2];
  const float* ctx   = (const float*)d_in[3];
  const float* props = (const float*)d_in[4];
  const int*   mask  = (const int*)d_in[5];
  const float* W1  = (const float*)d_in[6];  const float* as1 = (const float*)d_in[7];
  const float* ad1 = (const float*)d_in[8];  const float* b1  = (const float*)d_in[9];
  const float* g1  = (const float*)d_in[10]; const float* be1 = (const float*)d_in[11];
  const float* rm1 = (const float*)d_in[12]; const float* rv1 = (const float*)d_in[13];
  const float* W2  = (const float*)d_in[14]; const float* as2 = (const float*)d_in[15];
  const float* ad2 = (const float*)d_in[16]; const float* b2  = (const float*)d_in[17];
  const float* g2  = (const float*)d_in[18]; const float* be2 = (const float*)d_in[19];
  const float* rm2 = (const float*)d_in[20]; const float* rv2 = (const float*)d_in[21];
  const float* W3  = (const float*)d_in[22]; const float* as3 = (const float*)d_in[23];
  const float* ad3 = (const float*)d_in[24]; const float* b3  = (const float*)d_in[25];
  const float* g3  = (const float*)d_in[26]; const float* be3 = (const float*)d_in[27];
  const float* rm3 = (const float*)d_in[28]; const float* rv3 = (const float*)d_in[29];
  const float* cw1 = (const float*)d_in[30]; const float* cb1 = (const float*)d_in[31];
  const float* cw2 = (const float*)d_in[32]; const float* cb2 = (const float*)d_in[33];
  const float* pw1 = (const float*)d_in[34]; const float* pb1 = (const float*)d_in[35];
  const float* pw2 = (const float*)d_in[36]; const float* pb2 = (const float*)d_in[37];
  const float* mw1 = (const float*)d_in[38]; const float* mb1 = (const float*)d_in[39];
  const float* mw2 = (const float*)d_in[40]; const float* mb2 = (const float*)d_in[41];

  const int EP = E + N;
  const int H4 = 4 * HIDC;   // 512
  const int NB = (N + 1023) / 1024;
  const int GM = (N + 127) / 128;
  const int GG = (G + 127) / 128;

  (void)hipMemsetAsync(scal, 0, 8*sizeof(float), stream);      // includes flag
  (void)hipMemsetAsync(gemb, 0, (size_t)G*HIDC*sizeof(float), stream);
  (void)hipMemsetAsync(cnt,  0, (size_t)G*sizeof(float), stream);
  (void)hipMemsetAsync(deg,  0, (size_t)N*sizeof(int), stream);
  (void)hipMemsetAsync(ctr,  0, (size_t)N*sizeof(int), stream);
  mask_detect_kernel<<<(N/4 + 255)/256, 256, 0, stream>>>(mask, N/4, flag);

  // ---- CSR build (once; shared by all 3 layers) ----
  deg_count_kernel<<<(EP + 255)/256, 256, 0, stream>>>(ei, E, EP, deg);
  scan1_kernel<<<NB, 256, 0, stream>>>(deg, indptr, bsum, N);
  scan2_kernel<<<1, 64, 0, stream>>>(bsum, NB);
  scan3_kernel<<<(N + 255)/256, 256, 0, stream>>>(indptr, bsum, N, EP);
  fill_kernel<<<(EP + 255)/256, 256, 0, stream>>>(ei, E, EP, indptr, ctr, esrc);
  cnt_kernel<<<(N + 255)/256, 256, 0, stream>>>(batch, cnt, N);

  // ---- GAT layers (BN+ELU fused into aggregation epilogue) ----
  mfma_gemm_kernel<float, bf16, false, false><<<dim3(H4/64, GM), 256, 0, stream>>>(x, W1, nullptr, buf2, N, H4, 29, H4);
  scores_kernel<bf16><<<(N*4 + 3)/4, 256, 0, stream>>>(buf2, as1, ad1, ssrc, sdst, N, 4);
  csr_attn_agg_kernel<4,false><<<(N*4 + 3)/4, 256, 0, stream>>>(indptr, esrc, ssrc, sdst, buf2, buf1, N, b1, g1, be1, rm1, rv1, nullptr, nullptr);

  mfma_gemm_kernel<bf16, bf16, false, false><<<dim3(H4/64, GM), 256, 0, stream>>>(buf1, W2, nullptr, buf2, N, H4, H4, H4);
  scores_kernel<bf16><<<(N*4 + 3)/4, 256, 0, stream>>>(buf2, as2, ad2, ssrc, sdst, N, 4);
  csr_attn_agg_kernel<4,false><<<(N*4 + 3)/4, 256, 0, stream>>>(indptr, esrc, ssrc, sdst, buf2, buf1, N, b2, g2, be2, rm2, rv2, nullptr, nullptr);

  mfma_gemm_kernel<bf16, bf16, false, false><<<dim3(HIDC/64, GM), 256, 0, stream>>>(buf1, W3, nullptr, buf2, N, HIDC, H4, HIDC);
  scores_kernel<bf16><<<(N + 3)/4, 256, 0, stream>>>(buf2, as3, ad3, ssrc, sdst, N, 1);
  csr_attn_agg_kernel<1,true><<<(N + 3)/4, 256, 0, stream>>>(indptr, esrc, ssrc, sdst, buf2, buf1, N, b3, g3, be3, rm3, rv3, batch, gemb);

  // ---- global mean pool (sum fused into L3 agg) ----
  pool_div_kernel<<<(G*HIDC + 255)/256, 256, 0, stream>>>(gemb, cnt, G);

  bf16* headf = buf2;                                                 // [N,128] bf16 scratch
  float* zbuf  = (float*)((char*)buf1 + (size_t)N*HIDC*sizeof(bf16)); // [N,32] fp32 (buf1 tail)

  // ---- context head: relu(h@cw1+cb1) @ cw2 + cb2 -> BCE ----
  mfma_gemm_kernel<bf16, bf16, true, true><<<dim3(HIDC/64, GM), 256, 0, stream>>>(
      buf1, cw1, cb1, headf, N, HIDC, HIDC, HIDC);
  mfma_gemm_kernel<bf16, float, true, false><<<dim3(1, GM), 256, 0, stream>>>(
      headf, cw2, cb2, zbuf, N, 9, HIDC, 32);
  bce_reduce_kernel<<<2048, 256, 0, stream>>>(zbuf, ctx, &scal[0], N);

  // ---- masked reconstruction head ----
  mfma_gemm_kernel<bf16, bf16, true, true><<<dim3(HIDC/64, GM), 256, 0, stream>>>(
      buf1, mw1, mb1, headf, N, HIDC, HIDC, HIDC);
  mfma_gemm_kernel<bf16, float, true, false><<<dim3(1, GM), 256, 0, stream>>>(
      headf, mw2, mb2, zbuf, N, 29, HIDC, 32);
  mse_mask_reduce_kernel<<<2048, 256, 0, stream>>>(zbuf, x, mask, flag, &scal[2], &scal[3], N);

  // ---- property head ----
  mfma_gemm_kernel<float, float, true, true><<<dim3(HIDC/64, GG), 256, 0, stream>>>(
      gemb, pw1, pb1, r3, G, HIDC, HIDC, HIDC);
  mfma_gemm_kernel<float, float, true, false><<<dim3(1, GG), 256, 0, stream>>>(
      r3, pw2, pb2, pz, G, 9, HIDC, 32);
  mse_reduce_kernel<<<64, 256, 0, stream>>>(pz, props, &scal[1], G);

  finalize_kernel<<<1, 1, 0, stream>>>(scal, d_out, (float)N*9.f, (float)G*9.f);
}

extern "C" void kernel_launch(void* const* d_in, const int* in_sizes, int n_in,
                              void* d_out, int out_size, void* d_ws, size_t ws_size,
                              hipStream_t stream)
{
  const int N  = in_sizes[0] / 29;
  const int E  = in_sizes[1] / 2;
  const int G  = in_sizes[4] / 9;
  const int EP = E + N;
  const int H4 = 4 * HIDC;

  const size_t aux_bytes =
      (size_t)N*4*sizeof(float)*2            // ssrc, sdst
    + (size_t)(N+1)*sizeof(int)              // indptr
    + (size_t)N*sizeof(int)*2                // deg, ctr
    + 512*sizeof(int)                        // bsum
    + (size_t)EP*sizeof(int)                 // esrc
    + (size_t)G*HIDC*sizeof(float)*2         // gemb, r3
    + (size_t)G*32*sizeof(float)             // pz
    + (size_t)G*sizeof(float)                // cnt
    + 64*sizeof(float)
    + 4096;

  const size_t big = (size_t)N * H4;
  const size_t need = 2*big*sizeof(__hip_bfloat16) + aux_bytes;

  if (ws_size < need) {
    write_zero_kernel<<<1, 1, 0, stream>>>((float*)d_out);
    return;
  }

  char* base = (char*)d_ws;
  void* buf1 = (void*)base;          base += (big*sizeof(__hip_bfloat16) + 255) & ~(size_t)255;
  void* buf2 = (void*)base;          base += (big*sizeof(__hip_bfloat16) + 255) & ~(size_t)255;
  float* ssrc = (float*)base;        base += (size_t)N*4*sizeof(float);
  float* sdst = (float*)base;        base += (size_t)N*4*sizeof(float);
  int* indptr = (int*)base;          base += (size_t)(N+1)*sizeof(int);
  int* deg    = (int*)base;          base += (size_t)N*sizeof(int);
  int* ctr    = (int*)base;          base += (size_t)N*sizeof(int);
  int* bsum   = (int*)base;          base += 512*sizeof(int);
  int* esrc   = (int*)base;          base += (size_t)EP*sizeof(int);
  float* gemb = (float*)base;        base += (size_t)G*HIDC*sizeof(float);
  float* cnt  = (float*)base;        base += (size_t)G*sizeof(float);
  float* r3   = (float*)base;        base += (size_t)G*HIDC*sizeof(float);
  float* pz   = (float*)base;        base += (size_t)G*32*sizeof(float);
  float* scal = (float*)base;        base += 64*sizeof(float);
  int*   flag = (int*)&scal[4];

  run_pipeline(d_in, stream, (float*)d_out, (bf16*)buf1, (bf16*)buf2,
               ssrc, sdst, indptr, deg, ctr, bsum, esrc, gemb, cnt, r3, pz, scal, flag, N, E, G);
}

// Round 18
// 1239.620 us; speedup vs baseline: 1.0129x; 1.0129x over previous
//
#include <hip/hip_runtime.h>
#include <hip/hip_bf16.h>
#include <cstdint>
#include <cstddef>
#include <type_traits>

#define HIDC 128   // per-head channels

typedef __attribute__((ext_vector_type(8))) short short8v;
typedef __attribute__((ext_vector_type(4))) float float4v;

// ---------- typed load/store (fp32 or bf16 storage) ----------
__device__ __forceinline__ float loadT(const float* p){ return *p; }
__device__ __forceinline__ float loadT(const __hip_bfloat16* p){ return __bfloat162float(*p); }
__device__ __forceinline__ void  storeT(float* p, float v){ *p = v; }
__device__ __forceinline__ void  storeT(__hip_bfloat16* p, float v){ *p = __float2bfloat16(v); }

__device__ __forceinline__ short f2bf(float f){
  __hip_bfloat16 h = __float2bfloat16(f);
  return *reinterpret_cast<short*>(&h);
}
__device__ __forceinline__ float bfbits2f(short s){
  return __uint_as_float(((unsigned)(unsigned short)s) << 16);
}

// bijective XCD-chunk swizzle (m204): contiguous logical range per XCD
// (GEMM only — A/B on the agg kernel (R17) showed FETCH -6%, time neutral)
__device__ __forceinline__ int xcd_chunk(int orig, int nwg){
  int xcd = orig & 7, pos = orig >> 3;
  int q = nwg >> 3, r = nwg & 7;
  return (xcd < r ? xcd*(q+1) : r*(q+1) + (xcd - r)*q) + pos;
}

// swizzled LDS index (in shorts); k must be a multiple of 8 for b128 ops
__device__ __forceinline__ int swz(int row, int k){ return (row*32 + k) ^ ((row & 7) << 3); }

// ---------------- MFMA bf16 GEMM: C[M,0..Nb) = A[M,K] @ B[K,Nb] ----------------
// BM=128, BN=64, BK=32; 256 threads = 4 waves, each a 64x32 output tile.
// T1 XCD-chunk swizzle. DMA path (bf16 A, K%32==0, full row tile):
// 2-phase double-buffered pipeline (R15: proven WIN).
template<typename TA, typename TC, bool BIAS, bool RELU>
__global__ __launch_bounds__(256)
void mfma_gemm_kernel(const TA* __restrict__ A, const float* __restrict__ B,
                      const float* __restrict__ bias, TC* __restrict__ C,
                      int M, int Nb, int K, int ldc)
{
  __shared__ short As[2][128*32];
  __shared__ short Bs[2][64*32];

  const int nwg = gridDim.x * gridDim.y;
  int logical = xcd_chunk(blockIdx.y * gridDim.x + blockIdx.x, nwg);
  const int bx = logical % gridDim.x;
  const int by = logical / gridDim.x;

  const int tid  = threadIdx.x;
  const int brow = by * 128;
  const int bcol = bx * 64;
  const int lane = tid & 63;
  const int wave = tid >> 6;
  const int wm = (wave >> 1) * 64;
  const int wn = (wave & 1) * 32;
  const int l15 = lane & 15;
  const int kq  = lane >> 4;

  float4v acc[4][2];
  #pragma unroll
  for (int i = 0; i < 4; i++)
    #pragma unroll
    for (int j = 0; j < 2; j++)
      #pragma unroll
      for (int r2 = 0; r2 < 4; r2++) acc[i][j][r2] = 0.f;

  const int am  = tid >> 1;
  const int akb = (tid & 1) * 16;
  const int bn  = tid & 63;
  const int bkc = tid >> 6;

  const bool dma_ok = std::is_same<TA, __hip_bfloat16>::value &&
                      ((K & 31) == 0) && (brow + 128 <= M);
  int dma_r[2], dma_c[2];
  #pragma unroll
  for (int i = 0; i < 2; i++) {
    int j = (wave*2 + i)*64 + lane;
    int s2 = (j>>2)&1, s3 = (j>>3)&1, s4 = (j>>4)&1;
    int b2 = s2 ^ s4;
    int b1 = ((j>>1)&1) ^ s3;
    int b0 = (j&1) ^ b2;
    int src = (j & ~7) | (b2<<2) | (b1<<1) | b0;
    dma_r[i] = src >> 2;
    dma_c[i] = src & 3;
  }

  if (dma_ok) {
    const short* Ash = reinterpret_cast<const short*>(A);
    const int gcol = bcol + bn;
    const int nt = K >> 5;
    float bv[8];

    #pragma unroll
    for (int i = 0; i < 2; i++) {
      const short* gp = Ash + (size_t)(brow + dma_r[i])*K + dma_c[i]*8;
      __builtin_amdgcn_global_load_lds(
          (const __attribute__((address_space(1))) void*)gp,
          (__attribute__((address_space(3))) void*)&As[0][(wave*2 + i)*512],
          16, 0, 0);
    }
    #pragma unroll
    for (int j = 0; j < 8; j++) {
      int gk = bkc*8 + j;
      bv[j] = (gcol < Nb) ? B[(size_t)gk*Nb + gcol] : 0.f;
    }
    {
      short8v v;
      #pragma unroll
      for (int j = 0; j < 8; j++) v[j] = f2bf(bv[j]);
      *(short8v*)&Bs[0][swz(bn, bkc*8)] = v;
    }
    asm volatile("s_waitcnt vmcnt(0)" ::: "memory");
    __syncthreads();

    int cur = 0;
    for (int t = 0; t < nt; t++) {
      const bool pf = (t + 1 < nt);
      if (pf) {
        const int k0n = (t + 1) << 5;
        #pragma unroll
        for (int i = 0; i < 2; i++) {
          const short* gp = Ash + (size_t)(brow + dma_r[i])*K + k0n + dma_c[i]*8;
          __builtin_amdgcn_global_load_lds(
              (const __attribute__((address_space(1))) void*)gp,
              (__attribute__((address_space(3))) void*)&As[cur^1][(wave*2 + i)*512],
              16, 0, 0);
        }
        #pragma unroll
        for (int j = 0; j < 8; j++) {
          int gk = k0n + bkc*8 + j;
          bv[j] = (gcol < Nb) ? B[(size_t)gk*Nb + gcol] : 0.f;
        }
      }
      {
        short8v bfrag[2];
        #pragma unroll
        for (int ni = 0; ni < 2; ni++)
          bfrag[ni] = *(const short8v*)&Bs[cur][swz(wn + ni*16 + l15, kq*8)];
        #pragma unroll
        for (int mi = 0; mi < 4; mi++) {
          short8v afrag = *(const short8v*)&As[cur][swz(wm + mi*16 + l15, kq*8)];
          #pragma unroll
          for (int ni = 0; ni < 2; ni++)
            acc[mi][ni] = __builtin_amdgcn_mfma_f32_16x16x32_bf16(afrag, bfrag[ni], acc[mi][ni], 0, 0, 0);
        }
      }
      if (pf) {
        short8v v;
        #pragma unroll
        for (int j = 0; j < 8; j++) v[j] = f2bf(bv[j]);
        *(short8v*)&Bs[cur^1][swz(bn, bkc*8)] = v;
      }
      asm volatile("s_waitcnt vmcnt(0)" ::: "memory");
      __syncthreads();
      cur ^= 1;
    }
  } else {
    for (int k0 = 0; k0 < K; k0 += 32) {
      {
        const int gm = brow + am;
        short s[16];
        if constexpr (std::is_same<TA, __hip_bfloat16>::value) {
          if (gm < M && (k0 + akb + 16) <= K) {
            const short8v* p = reinterpret_cast<const short8v*>(
                reinterpret_cast<const short*>(A) + (size_t)gm*K + k0 + akb);
            short8v v0 = p[0];
            *(short8v*)&As[0][swz(am, akb)]     = v0;
            short8v v1 = p[1];
            *(short8v*)&As[0][swz(am, akb + 8)] = v1;
            goto a_done;
          }
        }
        #pragma unroll
        for (int j = 0; j < 16; j++) {
          int gk = k0 + akb + j;
          s[j] = (gm < M && gk < K) ? f2bf(loadT(&A[(size_t)gm*K + gk])) : (short)0;
        }
        {
          short8v v0, v1;
          #pragma unroll
          for (int j = 0; j < 8; j++) { v0[j] = s[j]; v1[j] = s[j+8]; }
          *(short8v*)&As[0][swz(am, akb)]     = v0;
          *(short8v*)&As[0][swz(am, akb + 8)] = v1;
        }
        a_done:;
      }
      {
        const int gcol = bcol + bn;
        short8v v;
        #pragma unroll
        for (int j = 0; j < 8; j++) {
          int gk = k0 + bkc*8 + j;
          v[j] = (gk < K && gcol < Nb) ? f2bf(B[(size_t)gk*Nb + gcol]) : (short)0;
        }
        *(short8v*)&Bs[0][swz(bn, bkc*8)] = v;
      }
      __syncthreads();

      short8v bfrag[2];
      #pragma unroll
      for (int ni = 0; ni < 2; ni++)
        bfrag[ni] = *(const short8v*)&Bs[0][swz(wn + ni*16 + l15, kq*8)];
      #pragma unroll
      for (int mi = 0; mi < 4; mi++) {
        short8v afrag = *(const short8v*)&As[0][swz(wm + mi*16 + l15, kq*8)];
        #pragma unroll
        for (int ni = 0; ni < 2; ni++)
          acc[mi][ni] = __builtin_amdgcn_mfma_f32_16x16x32_bf16(afrag, bfrag[ni], acc[mi][ni], 0, 0, 0);
      }
      __syncthreads();
    }
  }

  #pragma unroll
  for (int mi = 0; mi < 4; mi++) {
    #pragma unroll
    for (int r2 = 0; r2 < 4; r2++) {
      int row = brow + wm + mi*16 + kq*4 + r2;
      if (row >= M) continue;
      #pragma unroll
      for (int ni = 0; ni < 2; ni++) {
        int col = bcol + wn + ni*16 + l15;
        if (col >= Nb) continue;
        float v = acc[mi][ni][r2];
        if (BIAS) v += bias[col];
        if (RELU) v = fmaxf(v, 0.f);
        storeT(&C[(size_t)row*ldc + col], v);
      }
    }
  }
}

// ---------------- per-(node,head) attention scores ----------------
template<typename T>
__global__ void scores_kernel(const T* __restrict__ hW, const float* __restrict__ a_src,
                              const float* __restrict__ a_dst, float* __restrict__ s_src,
                              float* __restrict__ s_dst, int n, int H)
{
  const int lane = threadIdx.x & 63;
  const int wid = blockIdx.x*(blockDim.x>>6) + (threadIdx.x>>6);
  if (wid >= n*H) return;
  const int node = wid / H, h = wid % H;
  const T* row = hW + (size_t)node*H*HIDC + (size_t)h*HIDC;
  float ss = 0.f, sd = 0.f;
  for (int c = lane; c < HIDC; c += 64) {
    float v = loadT(&row[c]);
    ss += v * a_src[h*HIDC + c];
    sd += v * a_dst[h*HIDC + c];
  }
  #pragma unroll
  for (int off = 32; off; off >>= 1) {
    ss += __shfl_down(ss, off);
    sd += __shfl_down(sd, off);
  }
  if (lane == 0) { s_src[wid] = ss; s_dst[wid] = sd; }
}

// ---------------- CSR build (dst-bucketed incoming edges) ----------------
__global__ void deg_count_kernel(const int* __restrict__ ei, int E, int EP, int* __restrict__ deg)
{
  int e = blockIdx.x*blockDim.x + threadIdx.x;
  if (e >= EP) return;
  int d = (e < E) ? ei[E + e] : (e - E);
  atomicAdd(&deg[d], 1);
}

__global__ __launch_bounds__(256)
void scan1_kernel(const int* __restrict__ deg, int* __restrict__ indptr,
                  int* __restrict__ bsum, int n)
{
  __shared__ int sh[256];
  const int b = blockIdx.x, t = threadIdx.x;
  const int base = b*1024 + t*4;
  int v0 = (base+0 < n) ? deg[base+0] : 0;
  int v1 = (base+1 < n) ? deg[base+1] : 0;
  int v2 = (base+2 < n) ? deg[base+2] : 0;
  int v3 = (base+3 < n) ? deg[base+3] : 0;
  int tsum = v0+v1+v2+v3;
  sh[t] = tsum;
  __syncthreads();
  for (int off = 1; off < 256; off <<= 1) {
    int x = (t >= off) ? sh[t-off] : 0;
    __syncthreads();
    sh[t] += x;
    __syncthreads();
  }
  int run = sh[t] - tsum;
  if (base+0 < n) indptr[base+0] = run; run += v0;
  if (base+1 < n) indptr[base+1] = run; run += v1;
  if (base+2 < n) indptr[base+2] = run; run += v2;
  if (base+3 < n) indptr[base+3] = run;
  if (t == 255) bsum[b] = sh[255];
}

__global__ void scan2_kernel(int* __restrict__ bsum, int B)
{
  if (blockIdx.x == 0 && threadIdx.x == 0) {
    int run = 0;
    for (int i = 0; i < B; i++) { int v = bsum[i]; bsum[i] = run; run += v; }
  }
}

__global__ void scan3_kernel(int* __restrict__ indptr, const int* __restrict__ bsum,
                             int n, int total)
{
  int i = blockIdx.x*blockDim.x + threadIdx.x;
  if (i < n) indptr[i] += bsum[i >> 10];
  if (i == 0) indptr[n] = total;
}

__global__ void fill_kernel(const int* __restrict__ ei, int E, int EP,
                            const int* __restrict__ indptr, int* __restrict__ ctr,
                            int* __restrict__ esrc)
{
  int e = blockIdx.x*blockDim.x + threadIdx.x;
  if (e >= EP) return;
  int s, d;
  if (e < E) { s = ei[e]; d = ei[E + e]; } else { s = d = e - E; }
  int pos = indptr[d] + atomicAdd(&ctr[d], 1);
  esrc[pos] = s;
}

// ------- fused segment softmax + gather-aggregate + bias + BN(eval) + ELU -------
// ONE WAVE PER (dst, head); lane owns packed channel pair (2*lane, 2*lane+1)
// -> one dword load per edge, one dword store. ELU via __expf-1 (bf16-exact),
// BN scale via rsqrtf. deg<=8 fast 3-step reduction. POOL: fuse mean-pool sum.
typedef __hip_bfloat16 bf16;

template<int H, bool POOL>
__global__ void csr_attn_agg_kernel(const int* __restrict__ indptr, const int* __restrict__ esrc,
                                    const float* __restrict__ s_src, const float* __restrict__ s_dst,
                                    const bf16* __restrict__ hW, bf16* __restrict__ out, int n,
                                    const float* __restrict__ bias, const float* __restrict__ g,
                                    const float* __restrict__ be, const float* __restrict__ rm,
                                    const float* __restrict__ rv,
                                    const int* __restrict__ batch, float* __restrict__ gsum)
{
  constexpr int HD = H * HIDC;
  const int lane = threadIdx.x & 63;
  const int wid = blockIdx.x*(blockDim.x>>6) + (threadIdx.x>>6);
  if (wid >= n*H) return;
  const int dst = wid / H, h = wid - dst*H;
  const int beg = indptr[dst], end = indptr[dst+1];
  const int deg = end - beg;
  const float sdh = s_dst[dst*H + h];

  float acc0 = 0.f, acc1 = 0.f;
  const unsigned* hw32 = reinterpret_cast<const unsigned*>(hW);

  if (deg <= 64) {
    int sk = (lane < deg) ? esrc[beg + lane] : -1;
    float sc = -3.0e38f;
    if (sk >= 0) {
      float v = s_src[(size_t)sk*H + h] + sdh;
      sc = (v >= 0.f) ? v : 0.2f*v;
    }
    float m, e, den;
    if (deg <= 8) {
      m = sc;
      #pragma unroll
      for (int off = 1; off < 8; off <<= 1) m = fmaxf(m, __shfl_xor(m, off));
      m = __shfl(m, 0);
      e = (sk >= 0) ? __expf(sc - m) : 0.f;
      den = e;
      #pragma unroll
      for (int off = 1; off < 8; off <<= 1) den += __shfl_xor(den, off);
      den = __shfl(den, 0);
    } else {
      m = sc;
      #pragma unroll
      for (int off = 32; off; off >>= 1) m = fmaxf(m, __shfl_xor(m, off));
      e = (sk >= 0) ? __expf(sc - m) : 0.f;
      den = e;
      #pragma unroll
      for (int off = 32; off; off >>= 1) den += __shfl_xor(den, off);
    }
    const float rden = 1.f / (den + 1e-16f);
    for (int k = 0; k < deg; ++k) {
      float a = __shfl(e, k) * rden;
      int s = __shfl(sk, k);
      unsigned w = hw32[(size_t)s*(HD/2) + h*(HIDC/2) + lane];
      acc0 += a * bfbits2f((short)(w & 0xffff));
      acc1 += a * bfbits2f((short)((unsigned)w >> 16));
    }
  } else {
    float m = -3.0e38f;
    for (int k = beg + lane; k < end; k += 64) {
      float v = s_src[(size_t)esrc[k]*H + h] + sdh;
      v = (v >= 0.f) ? v : 0.2f*v;
      m = fmaxf(m, v);
    }
    #pragma unroll
    for (int off = 32; off; off >>= 1) m = fmaxf(m, __shfl_xor(m, off));
    float den = 0.f;
    for (int k = beg + lane; k < end; k += 64) {
      float v = s_src[(size_t)esrc[k]*H + h] + sdh;
      v = (v >= 0.f) ? v : 0.2f*v;
      den += __expf(v - m);
    }
    #pragma unroll
    for (int off = 32; off; off >>= 1) den += __shfl_xor(den, off);
    const float rden = 1.f / (den + 1e-16f);
    for (int k = beg; k < end; ++k) {
      int s = esrc[k];
      float v = s_src[(size_t)s*H + h] + sdh;
      v = (v >= 0.f) ? v : 0.2f*v;
      float a = __expf(v - m) * rden;
      unsigned w = hw32[(size_t)s*(HD/2) + h*(HIDC/2) + lane];
      acc0 += a * bfbits2f((short)(w & 0xffff));
      acc1 += a * bfbits2f((short)((unsigned)w >> 16));
    }
  }

  const int c0 = h*HIDC + 2*lane;
  const int c1 = c0 + 1;
  const float s0 = g[c0] * rsqrtf(rv[c0] + 1e-5f);
  const float s1 = g[c1] * rsqrtf(rv[c1] + 1e-5f);
  float y0 = (acc0 + bias[c0] - rm[c0]) * s0 + be[c0];
  float y1 = (acc1 + bias[c1] - rm[c1]) * s1 + be[c1];
  y0 = (y0 > 0.f) ? y0 : (__expf(y0) - 1.f);
  y1 = (y1 > 0.f) ? y1 : (__expf(y1) - 1.f);

  unsigned* orow32 = reinterpret_cast<unsigned*>(out) + (size_t)dst*(HD/2) + h*(HIDC/2);
  unsigned w = (unsigned)(unsigned short)f2bf(y0) | ((unsigned)(unsigned short)f2bf(y1) << 16);
  orow32[lane] = w;

  if constexpr (POOL) {
    const int grp = batch[dst];
    atomicAdd(&gsum[(size_t)grp*HIDC + 2*lane], y0);
    atomicAdd(&gsum[(size_t)grp*HIDC + 2*lane + 1], y1);
  }
}

// ---------------- per-graph node count ----------------
__global__ void cnt_kernel(const int* __restrict__ batch, float* __restrict__ cnt, int n)
{
  int i = blockIdx.x*blockDim.x + threadIdx.x;
  if (i >= n) return;
  atomicAdd(&cnt[batch[i]], 1.f);
}

__global__ void pool_div_kernel(float* __restrict__ gsum, const float* __restrict__ cnt, int G)
{
  int idx = blockIdx.x*blockDim.x + threadIdx.x;
  if (idx >= G*HIDC) return;
  gsum[idx] /= fmaxf(cnt[idx >> 7], 1.f);
}

// ---------------- mask dtype detection ----------------
__global__ void mask_detect_kernel(const int* __restrict__ m, int nwords, int* __restrict__ flag)
{
  int i = blockIdx.x*blockDim.x + threadIdx.x;
  if (i >= nwords) return;
  unsigned v = (unsigned)m[i];
  if (v > 1u) atomicOr(flag, 1);
}

// ---------------- loss reduces (grid-stride, 1-2 atomics per block) ----------------
__global__ __launch_bounds__(256)
void bce_reduce_kernel(const float* __restrict__ z, const float* __restrict__ ctx,
                       float* __restrict__ out_sum, int n)
{
  __shared__ float sh[256];
  float local = 0.f;
  const long long total = (long long)n * 9;
  for (long long i = (long long)blockIdx.x*blockDim.x + threadIdx.x; i < total;
       i += (long long)gridDim.x*blockDim.x) {
    int row = (int)(i / 9), j = (int)(i - (long long)row*9);
    float zz = z[(size_t)row*32 + j];
    float la = fmaxf(zz, 0.f) + log1pf(expf(-fabsf(zz)));
    local += la - zz * ctx[i];
  }
  sh[threadIdx.x] = local;
  __syncthreads();
  for (int s = 128; s; s >>= 1) {
    if ((int)threadIdx.x < s) sh[threadIdx.x] += sh[threadIdx.x + s];
    __syncthreads();
  }
  if (threadIdx.x == 0) atomicAdd(out_sum, sh[0]);
}

__global__ __launch_bounds__(256)
void mse_mask_reduce_kernel(const float* __restrict__ z, const float* __restrict__ x,
                            const int* __restrict__ mask, const int* __restrict__ bytemode,
                            float* __restrict__ out_sum, float* __restrict__ out_cnt, int n)
{
  __shared__ float sh[256], sh2[256];
  float local = 0.f, cl = 0.f;
  const bool bm = (*bytemode) != 0;
  const long long total = (long long)n * 29;
  for (long long i = (long long)blockIdx.x*blockDim.x + threadIdx.x; i < total;
       i += (long long)gridDim.x*blockDim.x) {
    int row = (int)(i / 29), j = (int)(i - (long long)row*29);
    int mk = bm ? (int)((const unsigned char*)mask)[row] : mask[row];
    if (mk != 0) {
      float dd = z[(size_t)row*32 + j] - x[i];
      local += dd*dd;
      if (j == 0) cl += 1.f;
    }
  }
  sh[threadIdx.x] = local;
  sh2[threadIdx.x] = cl;
  __syncthreads();
  for (int s = 128; s; s >>= 1) {
    if ((int)threadIdx.x < s) { sh[threadIdx.x] += sh[threadIdx.x + s]; sh2[threadIdx.x] += sh2[threadIdx.x + s]; }
    __syncthreads();
  }
  if (threadIdx.x == 0) { atomicAdd(out_sum, sh[0]); atomicAdd(out_cnt, sh2[0]); }
}

__global__ __launch_bounds__(256)
void mse_reduce_kernel(const float* __restrict__ z, const float* __restrict__ props,
                       float* __restrict__ out_sum, int g)
{
  __shared__ float sh[256];
  float local = 0.f;
  const long long total = (long long)g * 9;
  for (long long i = (long long)blockIdx.x*blockDim.x + threadIdx.x; i < total;
       i += (long long)gridDim.x*blockDim.x) {
    int row = (int)(i / 9), j = (int)(i - (long long)row*9);
    float dd = z[(size_t)row*32 + j] - props[i];
    local += dd*dd;
  }
  sh[threadIdx.x] = local;
  __syncthreads();
  for (int s = 128; s; s >>= 1) {
    if ((int)threadIdx.x < s) sh[threadIdx.x] += sh[threadIdx.x + s];
    __syncthreads();
  }
  if (threadIdx.x == 0) atomicAdd(out_sum, sh[0]);
}

__global__ void finalize_kernel(const float* __restrict__ scal, float* __restrict__ out,
                                float nf, float gf)
{
  out[0] = scal[0]/nf + scal[1]/gf + 0.5f*(scal[2]/(scal[3]*29.f));
}

__global__ void write_zero_kernel(float* __restrict__ out){ out[0] = 0.f; }

// ---------------- pipeline (bf16 node-feature storage) ----------------
static void run_pipeline(void* const* d_in, hipStream_t stream, float* d_out,
                         bf16* buf1, bf16* buf2, float* ssrc, float* sdst,
                         int* indptr, int* deg, int* ctr, int* bsum, int* esrc,
                         float* gemb, float* cnt, float* r3, float* pz, float* scal, int* flag,
                         int N, int E, int G)
{
  const float* x     = (const float*)d_in[0];
  const int*   ei    = (const int*)d_in[1];
  const int*   batch = (const int*)d_in[2];
  const float* ctx   = (const float*)d_in[3];
  const float* props = (const float*)d_in[4];
  const int*   mask  = (const int*)d_in[5];
  const float* W1  = (const float*)d_in[6];  const float* as1 = (const float*)d_in[7];
  const float* ad1 = (const float*)d_in[8];  const float* b1  = (const float*)d_in[9];
  const float* g1  = (const float*)d_in[10]; const float* be1 = (const float*)d_in[11];
  const float* rm1 = (const float*)d_in[12]; const float* rv1 = (const float*)d_in[13];
  const float* W2  = (const float*)d_in[14]; const float* as2 = (const float*)d_in[15];
  const float* ad2 = (const float*)d_in[16]; const float* b2  = (const float*)d_in[17];
  const float* g2  = (const float*)d_in[18]; const float* be2 = (const float*)d_in[19];
  const float* rm2 = (const float*)d_in[20]; const float* rv2 = (const float*)d_in[21];
  const float* W3  = (const float*)d_in[22]; const float* as3 = (const float*)d_in[23];
  const float* ad3 = (const float*)d_in[24]; const float* b3  = (const float*)d_in[25];
  const float* g3  = (const float*)d_in[26]; const float* be3 = (const float*)d_in[27];
  const float* rm3 = (const float*)d_in[28]; const float* rv3 = (const float*)d_in[29];
  const float* cw1 = (const float*)d_in[30]; const float* cb1 = (const float*)d_in[31];
  const float* cw2 = (const float*)d_in[32]; const float* cb2 = (const float*)d_in[33];
  const float* pw1 = (const float*)d_in[34]; const float* pb1 = (const float*)d_in[35];
  const float* pw2 = (const float*)d_in[36]; const float* pb2 = (const float*)d_in[37];
  const float* mw1 = (const float*)d_in[38]; const float* mb1 = (const float*)d_in[39];
  const float* mw2 = (const float*)d_in[40]; const float* mb2 = (const float*)d_in[41];

  const int EP = E + N;
  const int H4 = 4 * HIDC;   // 512
  const int NB = (N + 1023) / 1024;
  const int GM = (N + 127) / 128;
  const int GG = (G + 127) / 128;

  (void)hipMemsetAsync(scal, 0, 8*sizeof(float), stream);      // includes flag
  (void)hipMemsetAsync(gemb, 0, (size_t)G*HIDC*sizeof(float), stream);
  (void)hipMemsetAsync(cnt,  0, (size_t)G*sizeof(float), stream);
  (void)hipMemsetAsync(deg,  0, (size_t)N*sizeof(int), stream);
  (void)hipMemsetAsync(ctr,  0, (size_t)N*sizeof(int), stream);
  mask_detect_kernel<<<(N/4 + 255)/256, 256, 0, stream>>>(mask, N/4, flag);

  // ---- CSR build (once; shared by all 3 layers) ----
  deg_count_kernel<<<(EP + 255)/256, 256, 0, stream>>>(ei, E, EP, deg);
  scan1_kernel<<<NB, 256, 0, stream>>>(deg, indptr, bsum, N);
  scan2_kernel<<<1, 64, 0, stream>>>(bsum, NB);
  scan3_kernel<<<(N + 255)/256, 256, 0, stream>>>(indptr, bsum, N, EP);
  fill_kernel<<<(EP + 255)/256, 256, 0, stream>>>(ei, E, EP, indptr, ctr, esrc);
  cnt_kernel<<<(N + 255)/256, 256, 0, stream>>>(batch, cnt, N);

  // ---- GAT layers (BN+ELU fused into aggregation epilogue) ----
  mfma_gemm_kernel<float, bf16, false, false><<<dim3(H4/64, GM), 256, 0, stream>>>(x, W1, nullptr, buf2, N, H4, 29, H4);
  scores_kernel<bf16><<<(N*4 + 3)/4, 256, 0, stream>>>(buf2, as1, ad1, ssrc, sdst, N, 4);
  csr_attn_agg_kernel<4,false><<<(N*4 + 3)/4, 256, 0, stream>>>(indptr, esrc, ssrc, sdst, buf2, buf1, N, b1, g1, be1, rm1, rv1, nullptr, nullptr);

  mfma_gemm_kernel<bf16, bf16, false, false><<<dim3(H4/64, GM), 256, 0, stream>>>(buf1, W2, nullptr, buf2, N, H4, H4, H4);
  scores_kernel<bf16><<<(N*4 + 3)/4, 256, 0, stream>>>(buf2, as2, ad2, ssrc, sdst, N, 4);
  csr_attn_agg_kernel<4,false><<<(N*4 + 3)/4, 256, 0, stream>>>(indptr, esrc, ssrc, sdst, buf2, buf1, N, b2, g2, be2, rm2, rv2, nullptr, nullptr);

  mfma_gemm_kernel<bf16, bf16, false, false><<<dim3(HIDC/64, GM), 256, 0, stream>>>(buf1, W3, nullptr, buf2, N, HIDC, H4, HIDC);
  scores_kernel<bf16><<<(N + 3)/4, 256, 0, stream>>>(buf2, as3, ad3, ssrc, sdst, N, 1);
  csr_attn_agg_kernel<1,true><<<(N + 3)/4, 256, 0, stream>>>(indptr, esrc, ssrc, sdst, buf2, buf1, N, b3, g3, be3, rm3, rv3, batch, gemb);

  // ---- global mean pool (sum fused into L3 agg) ----
  pool_div_kernel<<<(G*HIDC + 255)/256, 256, 0, stream>>>(gemb, cnt, G);

  bf16* headf = buf2;                                                 // [N,128] bf16 scratch
  float* zbuf  = (float*)((char*)buf1 + (size_t)N*HIDC*sizeof(bf16)); // [N,32] fp32 (buf1 tail)

  // ---- context head: relu(h@cw1+cb1) @ cw2 + cb2 -> BCE ----
  mfma_gemm_kernel<bf16, bf16, true, true><<<dim3(HIDC/64, GM), 256, 0, stream>>>(
      buf1, cw1, cb1, headf, N, HIDC, HIDC, HIDC);
  mfma_gemm_kernel<bf16, float, true, false><<<dim3(1, GM), 256, 0, stream>>>(
      headf, cw2, cb2, zbuf, N, 9, HIDC, 32);
  bce_reduce_kernel<<<2048, 256, 0, stream>>>(zbuf, ctx, &scal[0], N);

  // ---- masked reconstruction head ----
  mfma_gemm_kernel<bf16, bf16, true, true><<<dim3(HIDC/64, GM), 256, 0, stream>>>(
      buf1, mw1, mb1, headf, N, HIDC, HIDC, HIDC);
  mfma_gemm_kernel<bf16, float, true, false><<<dim3(1, GM), 256, 0, stream>>>(
      headf, mw2, mb2, zbuf, N, 29, HIDC, 32);
  mse_mask_reduce_kernel<<<2048, 256, 0, stream>>>(zbuf, x, mask, flag, &scal[2], &scal[3], N);

  // ---- property head ----
  mfma_gemm_kernel<float, float, true, true><<<dim3(HIDC/64, GG), 256, 0, stream>>>(
      gemb, pw1, pb1, r3, G, HIDC, HIDC, HIDC);
  mfma_gemm_kernel<float, float, true, false><<<dim3(1, GG), 256, 0, stream>>>(
      r3, pw2, pb2, pz, G, 9, HIDC, 32);
  mse_reduce_kernel<<<64, 256, 0, stream>>>(pz, props, &scal[1], G);

  finalize_kernel<<<1, 1, 0, stream>>>(scal, d_out, (float)N*9.f, (float)G*9.f);
}

extern "C" void kernel_launch(void* const* d_in, const int* in_sizes, int n_in,
                              void* d_out, int out_size, void* d_ws, size_t ws_size,
                              hipStream_t stream)
{
  const int N  = in_sizes[0] / 29;
  const int E  = in_sizes[1] / 2;
  const int G  = in_sizes[4] / 9;
  const int EP = E + N;
  const int H4 = 4 * HIDC;

  const size_t aux_bytes =
      (size_t)N*4*sizeof(float)*2            // ssrc, sdst
    + (size_t)(N+1)*sizeof(int)              // indptr
    + (size_t)N*sizeof(int)*2                // deg, ctr
    + 512*sizeof(int)                        // bsum
    + (size_t)EP*sizeof(int)                 // esrc
    + (size_t)G*HIDC*sizeof(float)*2         // gemb, r3
    + (size_t)G*32*sizeof(float)             // pz
    + (size_t)G*sizeof(float)                // cnt
    + 64*sizeof(float)
    + 4096;

  const size_t big = (size_t)N * H4;
  const size_t need = 2*big*sizeof(__hip_bfloat16) + aux_bytes;

  if (ws_size < need) {
    write_zero_kernel<<<1, 1, 0, stream>>>((float*)d_out);
    return;
  }

  char* base = (char*)d_ws;
  void* buf1 = (void*)base;          base += (big*sizeof(__hip_bfloat16) + 255) & ~(size_t)255;
  void* buf2 = (void*)base;          base += (big*sizeof(__hip_bfloat16) + 255) & ~(size_t)255;
  float* ssrc = (float*)base;        base += (size_t)N*4*sizeof(float);
  float* sdst = (float*)base;        base += (size_t)N*4*sizeof(float);
  int* indptr = (int*)base;          base += (size_t)(N+1)*sizeof(int);
  int* deg    = (int*)base;          base += (size_t)N*sizeof(int);
  int* ctr    = (int*)base;          base += (size_t)N*sizeof(int);
  int* bsum   = (int*)base;          base += 512*sizeof(int);
  int* esrc   = (int*)base;          base += (size_t)EP*sizeof(int);
  float* gemb = (float*)base;        base += (size_t)G*HIDC*sizeof(float);
  float* cnt  = (float*)base;        base += (size_t)G*sizeof(float);
  float* r3   = (float*)base;        base += (size_t)G*HIDC*sizeof(float);
  float* pz   = (float*)base;        base += (size_t)G*32*sizeof(float);
  float* scal = (float*)base;        base += 64*sizeof(float);
  int*   flag = (int*)&scal[4];

  run_pipeline(d_in, stream, (float*)d_out, (bf16*)buf1, (bf16*)buf2,
               ssrc, sdst, indptr, deg, ctr, bsum, esrc, gemb, cnt, r3, pz, scal, flag, N, E, G);
}